// Round 7
// baseline (774.940 us; speedup 1.0000x reference)
//
#include <hip/hip_runtime.h>

#define S_TOT 3872
#define C_DIM 1536
#define NHEAD 12
#define DHEAD 128
#define TT 8
#define HH 22
#define WW 22
#define NKT 61          // ceil(3872/64) key tiles
#define NQT 31          // ceil(3872/128) query tiles (last has 32 q)

typedef __bf16 bf16x8 __attribute__((ext_vector_type(8)));
typedef float  f32x4  __attribute__((ext_vector_type(4)));
typedef unsigned short u16x8 __attribute__((ext_vector_type(8)));

__device__ __forceinline__ float bf2f(unsigned short u) {
    unsigned int v = ((unsigned int)u) << 16;
    float f; __builtin_memcpy(&f, &v, 4); return f;
}
__device__ __forceinline__ unsigned short f2bf(float f) {
    unsigned int u; __builtin_memcpy(&u, &f, 4);
    u += 0x7fffu + ((u >> 16) & 1u);
    return (unsigned short)(u >> 16);
}
__device__ __forceinline__ unsigned int pk2_trunc(float a, float b) {
    unsigned int ua, ub;
    __builtin_memcpy(&ua, &a, 4); __builtin_memcpy(&ub, &b, 4);
    return (ua >> 16) | (ub & 0xffff0000u);
}
__device__ __forceinline__ float ldin(const void* p, size_t i, int isf32) {
    if (isf32) return ((const float*)p)[i];
    return bf2f(((const unsigned short*)p)[i]);
}
__device__ __forceinline__ float fexp2(float x) {
#if __has_builtin(__builtin_amdgcn_exp2f)
    return __builtin_amdgcn_exp2f(x);
#else
    return exp2f(x);
#endif
}
__device__ __forceinline__ void async16(const void* g, void* l) {
    __builtin_amdgcn_global_load_lds(
        (const __attribute__((address_space(1))) unsigned int*)g,
        (__attribute__((address_space(3))) unsigned int*)l, 16, 0, 0);
}

// ------- dtype detector + bias/gain conversion (1 block) --------------
__global__ void detect_vecs(const unsigned short* __restrict__ x,
                            const void* p0, const void* p1, const void* p2,
                            const void* p3, const void* p4, const void* p5,
                            int* __restrict__ flag, unsigned short* __restrict__ vecs) {
    __shared__ int cnt;
    if (threadIdx.x == 0) cnt = 0;
    __syncthreads();
    int c = 0;
    for (int i = 0; i < 8; ++i) {
        unsigned short u = x[threadIdx.x * 8 + i];
        int e = (u >> 7) & 0xFF;
        if (e >= 112 && e <= 143) c++;
    }
    atomicAdd(&cnt, c);
    __syncthreads();
    int isf32 = (cnt >= 1900) ? 0 : 1;
    if (threadIdx.x == 0) *flag = isf32;
    const void* ps[6] = {p0, p1, p2, p3, p4, p5};
    for (int v = 0; v < 6; ++v)
        for (int j = threadIdx.x; j < C_DIM; j += 256)
            vecs[v * C_DIM + j] = f2bf(ldin(ps[v], j, isf32));
}

// -------- two weight matrices -> bf16, grid (1152, 2) -----------------
__global__ __launch_bounds__(256) void wconv2(const void* __restrict__ sA,
                                              const void* __restrict__ sB,
                                              const int* __restrict__ flag,
                                              unsigned short* __restrict__ dA,
                                              unsigned short* __restrict__ dB) {
    const void* src = blockIdx.y ? sB : sA;
    unsigned short* dst = blockIdx.y ? dB : dA;
    size_t i = ((size_t)blockIdx.x * 256 + threadIdx.x) * 8;
    if (*flag) {
        const float* s = (const float*)src + i;
        float4 a = *(const float4*)s, b = *(const float4*)(s + 4);
        u16x8 o;
        o[0]=f2bf(a.x); o[1]=f2bf(a.y); o[2]=f2bf(a.z); o[3]=f2bf(a.w);
        o[4]=f2bf(b.x); o[5]=f2bf(b.y); o[6]=f2bf(b.z); o[7]=f2bf(b.w);
        *(u16x8*)(dst + i) = o;
    } else {
        *(u16x8*)(dst + i) = *(const u16x8*)((const unsigned short*)src + i);
    }
}

// ---------------- LayerNorm stats: grid 61, block (64 s x 4 cg) -------
__global__ __launch_bounds__(256) void ln_stats(const void* __restrict__ x,
                                                const int* __restrict__ flag,
                                                float* __restrict__ meanb,
                                                float* __restrict__ rstdb) {
    int isf32 = *flag;
    int sl = threadIdx.x & 63, cg = threadIdx.x >> 6;
    int s = blockIdx.x * 64 + sl;
    float sum = 0.f, sumsq = 0.f;
    if (s < S_TOT) {
        for (int c = cg; c < C_DIM; c += 4) {
            float v = ldin(x, (size_t)c * S_TOT + s, isf32);
            sum += v; sumsq += v * v;
        }
    }
    __shared__ float r0[4][64], r1[4][64];
    r0[cg][sl] = sum; r1[cg][sl] = sumsq;
    __syncthreads();
    if (cg == 0 && s < S_TOT) {
        float st = r0[0][sl] + r0[1][sl] + r0[2][sl] + r0[3][sl];
        float sq = r1[0][sl] + r1[1][sl] + r1[2][sl] + r1[3][sl];
        float m = st * (1.0f / C_DIM);
        float var = sq * (1.0f / C_DIM) - m * m;
        meanb[s] = m;
        rstdb[s] = rsqrtf(var + 1e-6f);
    }
}

// ------------- Normalize + transpose (C,S) -> (S,C) bf16 --------------
__global__ __launch_bounds__(256) void ln_norm_t(const void* __restrict__ x,
                                                 const int* __restrict__ flag,
                                                 const float* __restrict__ meanb,
                                                 const float* __restrict__ rstdb,
                                                 unsigned short* __restrict__ xn) {
    int isf32 = *flag;
    __shared__ float tile[32][33];
    int s0 = blockIdx.x * 32, c0 = blockIdx.y * 32;
    int tx = threadIdx.x, ty = threadIdx.y;   // (32,8)
    for (int r = 0; r < 4; ++r) {
        int cl = ty + 8 * r;
        tile[cl][tx] = ldin(x, (size_t)(c0 + cl) * S_TOT + (s0 + tx), isf32);
    }
    __syncthreads();
    for (int r = 0; r < 4; ++r) {
        int sl = ty + 8 * r;
        int s = s0 + sl, c = c0 + tx;
        xn[(size_t)s * C_DIM + c] = f2bf((tile[tx][sl] - meanb[s]) * rstdb[s]);
    }
}

// ------- MFMA GEMM 64x128, BK=64, group-padded DMA staging ------------
// 16 MFMA per barrier pair (2x R6), 24 K-steps. Chunks of 8 rows x 128B
// padded to 1056B so frag reads spread over 8 bank groups evenly.
__global__ __launch_bounds__(256) void gemm64(const unsigned short* __restrict__ A,
                                              const unsigned short* __restrict__ W,
                                              const unsigned short* __restrict__ bias,
                                              unsigned short* __restrict__ D,
                                              int transV) {
    __shared__ __align__(16) unsigned char As_[8 * 1056];    // 64 rows x 64
    __shared__ __align__(16) unsigned char Bs_[16 * 1056];   // 128 rows x 64
    int m0 = blockIdx.x * 64, n0 = blockIdx.y * 128;
    int tid = threadIdx.x;
    int wave = tid >> 6, lane = tid & 63;
    int lm = lane & 15, lq = lane >> 4;
    int l8 = lane >> 3, c8 = (lane & 7) * 8;    // DMA: row-in-chunk, col

    f32x4 acc[4][2];
    #pragma unroll
    for (int a = 0; a < 4; ++a)
        #pragma unroll
        for (int b = 0; b < 2; ++b) acc[a][b] = (f32x4){0.f, 0.f, 0.f, 0.f};

    for (int k0 = 0; k0 < C_DIM; k0 += 64) {
        __syncthreads();
        #pragma unroll
        for (int t = 0; t < 6; ++t) {
            int g = wave * 6 + t;   // 0..23
            if (g < 8) {
                int row = m0 + g * 8 + l8; if (row > S_TOT - 1) row = S_TOT - 1;
                async16(A + (size_t)row * C_DIM + k0 + c8, As_ + g * 1056);
            } else {
                int gb = g - 8;
                int row = n0 + gb * 8 + l8;
                async16(W + (size_t)row * C_DIM + k0 + c8, Bs_ + gb * 1056);
            }
        }
        __syncthreads();
        bf16x8 af[4][2], bf[2][2];
        #pragma unroll
        for (int mb = 0; mb < 4; ++mb)
            #pragma unroll
            for (int kc = 0; kc < 2; ++kc)
                af[mb][kc] = *(const bf16x8*)(As_ + (2 * mb + (lm >> 3)) * 1056
                                              + (lm & 7) * 128 + kc * 64 + lq * 16);
        #pragma unroll
        for (int nb = 0; nb < 2; ++nb)
            #pragma unroll
            for (int kc = 0; kc < 2; ++kc)
                bf[nb][kc] = *(const bf16x8*)(Bs_ + (4 * wave + 2 * nb + (lm >> 3)) * 1056
                                              + (lm & 7) * 128 + kc * 64 + lq * 16);
        #pragma unroll
        for (int kc = 0; kc < 2; ++kc)
            #pragma unroll
            for (int mb = 0; mb < 4; ++mb)
                #pragma unroll
                for (int nb = 0; nb < 2; ++nb)
                    acc[mb][nb] = __builtin_amdgcn_mfma_f32_16x16x32_bf16(af[mb][kc], bf[nb][kc], acc[mb][nb], 0, 0, 0);
    }

    if (!transV) {
        #pragma unroll
        for (int mb = 0; mb < 4; ++mb)
            #pragma unroll
            for (int nb = 0; nb < 2; ++nb) {
                int gn = n0 + wave * 32 + nb * 16 + lm;
                float bv = bf2f(bias[gn]);
                #pragma unroll
                for (int r = 0; r < 4; ++r) {
                    int gm = m0 + mb * 16 + lq * 4 + r;
                    if (gm < S_TOT) D[(size_t)gm * C_DIM + gn] = f2bf(acc[mb][nb][r] + bv);
                }
            }
    } else {
        #pragma unroll
        for (int mb = 0; mb < 4; ++mb) {
            int gm0 = m0 + mb * 16 + lq * 4;
            if (gm0 >= S_TOT) continue;
            #pragma unroll
            for (int nb = 0; nb < 2; ++nb) {
                int gn = n0 + wave * 32 + nb * 16 + lm;
                float bv = bf2f(bias[gn]);
                ushort4 pk;
                pk.x = f2bf(acc[mb][nb][0] + bv);
                pk.y = f2bf(acc[mb][nb][1] + bv);
                pk.z = f2bf(acc[mb][nb][2] + bv);
                pk.w = f2bf(acc[mb][nb][3] + bv);
                *(ushort4*)(D + (size_t)gn * S_TOT + gm0) = pk;
            }
        }
    }
}

// ---------- RMSNorm + RoPE for Q and K in one launch, in-place --------
__global__ __launch_bounds__(256) void rope2(unsigned short* __restrict__ qbuf,
                                             unsigned short* __restrict__ kbuf,
                                             const unsigned short* __restrict__ gq,
                                             const unsigned short* __restrict__ gk,
                                             float qsc) {
    int s = blockIdx.x;
    unsigned short* row = (blockIdx.y ? kbuf : qbuf) + (size_t)s * C_DIM;
    const unsigned short* g = blockIdx.y ? gk : gq;
    float premul = blockIdx.y ? 1.0f : qsc;
    int tid = threadIdx.x;
    float ss = 0.f;
    for (int i = 0; i < 6; ++i) {
        float v = bf2f(row[tid + 256 * i]);
        ss += v * v;
    }
    for (int off = 32; off; off >>= 1) ss += __shfl_down(ss, off, 64);
    __shared__ float wsum[4];
    __shared__ float scale_sh;
    if ((tid & 63) == 0) wsum[tid >> 6] = ss;
    __syncthreads();
    if (tid == 0) {
        float tot = wsum[0] + wsum[1] + wsum[2] + wsum[3];
        scale_sh = rsqrtf(tot * (1.0f / C_DIM) + 1e-6f) * premul;
    }
    __syncthreads();
    float scale = scale_sh;

    int t  = s / (HH * WW);
    int rm = s % (HH * WW);
    int hh = rm / WW, ww = rm % WW;

    float e[3][2];
    int cols[3];
    for (int i = 0; i < 3; ++i) {
        int p = tid + 256 * i;
        int j = p & 63;
        int col0 = (p >> 6) * DHEAD + 2 * j;
        cols[i] = col0;
        float e0 = bf2f(row[col0])     * scale * bf2f(g[col0]);
        float e1 = bf2f(row[col0 + 1]) * scale * bf2f(g[col0 + 1]);
        float pos, fr;
        if (j < 22)       { pos = (float)t;  fr = (float)j        * (1.0f / 22.0f); }
        else if (j < 43)  { pos = (float)hh; fr = (float)(j - 22) * (1.0f / 21.0f); }
        else              { pos = (float)ww; fr = (float)(j - 43) * (1.0f / 21.0f); }
        float ang = pos * expf(fr * -9.210340371976184f);
        float c = cosf(ang), sn = sinf(ang);
        e[i][0] = e0 * c - e1 * sn;
        e[i][1] = e0 * sn + e1 * c;
    }
    for (int i = 0; i < 3; ++i) {
        row[cols[i]]     = f2bf(e[i][0]);
        row[cols[i] + 1] = f2bf(e[i][1]);
    }
}

// ---------------- MFMA flash attention v4: 32 q per wave --------------
// Q-tile 128/block (372 blocks, all co-resident at 2 blocks/CU). K/V
// frag reads shared across the two 16-col q groups -> LDS bytes/FLOP
// halved vs v3. alpha==1 ballot skips O-rescale. LDS 60.5 KB.
__global__ __launch_bounds__(256) void attn_mfma(const unsigned short* __restrict__ q,
                                                 const unsigned short* __restrict__ kp,
                                                 const unsigned short* __restrict__ vt,
                                                 unsigned short* __restrict__ o) {
    __shared__ __align__(16) unsigned char Ks[16896];       // 16 groups * 1056B
    __shared__ __align__(16) unsigned short Vs[128 * 88];   // [d][keys], pad 24
    __shared__ __align__(16) unsigned short Ps[4][32 * 88]; // [wave][q32][keys]

    int h  = blockIdx.x / NQT;
    int qt = blockIdx.x % NQT;
    int q0 = qt * 128;
    int tid = threadIdx.x;
    int wave = tid >> 6, lane = tid & 63;
    int lm = lane & 15, lq = lane >> 4;

    // Q as B-operand fragments, 2 groups of 16 q-cols; pre-scaled by qsc
    bf16x8 qf[2][4];
    #pragma unroll
    for (int g = 0; g < 2; ++g) {
        int qr = q0 + wave * 32 + g * 16 + lm; if (qr >= S_TOT) qr = S_TOT - 1;
        const unsigned short* qptr = q + (size_t)qr * C_DIM + h * DHEAD + lq * 8;
        #pragma unroll
        for (int kc = 0; kc < 4; ++kc) qf[g][kc] = *(const bf16x8*)(qptr + kc * 32);
    }

    int kgrow = lane >> 4;
    size_t kcol = (size_t)(h * DHEAD + (lane & 15) * 8);
    int vd  = tid >> 1;
    int vk0 = (tid & 1) * 32;
    const unsigned short* vrow = vt + (size_t)(h * DHEAD + vd) * S_TOT;
    int ksoff[4], kqoff[4];
    #pragma unroll
    for (int nt = 0; nt < 4; ++nt) ksoff[nt] = (nt * 4 + (lm >> 2)) * 1056 + (lm & 3) * 256;
    #pragma unroll
    for (int kc = 0; kc < 4; ++kc) kqoff[kc] = (kc * 4 + lq) * 16;

    f32x4 oacc[2][8];
    #pragma unroll
    for (int g = 0; g < 2; ++g)
        #pragma unroll
        for (int i = 0; i < 8; ++i) oacc[g][i] = (f32x4){0.f, 0.f, 0.f, 0.f};
    float m_run[2] = {-__builtin_inff(), -__builtin_inff()};
    float l_run[2] = {0.f, 0.f};

    for (int kt = 0; kt < NKT; ++kt) {
        int k0 = kt * 64;
        __syncthreads();               // prev tile reads complete
        #pragma unroll
        for (int t = 0; t < 4; ++t) {
            int g = wave * 4 + t;
            int grow = k0 + g * 4 + kgrow; if (grow > S_TOT - 1) grow = S_TOT - 1;
            async16(kp + (size_t)grow * C_DIM + kcol, Ks + g * 1056);
        }
        #pragma unroll
        for (int c = 0; c < 4; ++c) {
            int gk = k0 + vk0 + c * 8; if (gk > S_TOT - 8) gk = S_TOT - 8;
            uint4 val = *(const uint4*)(vrow + gk);
            *(uint4*)(&Vs[vd * 88 + vk0 + c * 8]) = val;
        }
        __syncthreads();               // DMA + V landed

        // S^T[key][q] for both q groups; K-frags read once, shared
        f32x4 sacc[2][4];
        #pragma unroll
        for (int g = 0; g < 2; ++g)
            #pragma unroll
            for (int nt = 0; nt < 4; ++nt) sacc[g][nt] = (f32x4){0.f, 0.f, 0.f, 0.f};
        #pragma unroll
        for (int kc = 0; kc < 4; ++kc) {
            bf16x8 kf[4];
            #pragma unroll
            for (int nt = 0; nt < 4; ++nt)
                kf[nt] = *(const bf16x8*)(Ks + ksoff[nt] + kqoff[kc]);
            #pragma unroll
            for (int g = 0; g < 2; ++g)
                #pragma unroll
                for (int nt = 0; nt < 4; ++nt)
                    sacc[g][nt] = __builtin_amdgcn_mfma_f32_16x16x32_bf16(kf[nt], qf[g][kc], sacc[g][nt], 0, 0, 0);
        }
        if (kt == NKT - 1) {
            #pragma unroll
            for (int nt = 0; nt < 4; ++nt)
                #pragma unroll
                for (int r = 0; r < 4; ++r)
                    if (k0 + nt * 16 + lq * 4 + r >= S_TOT) {
                        sacc[0][nt][r] = -__builtin_inff();
                        sacc[1][nt][r] = -__builtin_inff();
                    }
        }
        // online softmax, base-2, scalar state per q group
        float alpha[2];
        #pragma unroll
        for (int g = 0; g < 2; ++g) {
            float rmax = sacc[g][0][0];
            #pragma unroll
            for (int nt = 0; nt < 4; ++nt)
                #pragma unroll
                for (int r = 0; r < 4; ++r) rmax = fmaxf(rmax, sacc[g][nt][r]);
            rmax = fmaxf(rmax, __shfl_xor(rmax, 16, 64));
            rmax = fmaxf(rmax, __shfl_xor(rmax, 32, 64));
            float mn = fmaxf(m_run[g], rmax);
            alpha[g] = fexp2(m_run[g] - mn);
            float rs = 0.f;
            #pragma unroll
            for (int nt = 0; nt < 4; ++nt)
                #pragma unroll
                for (int r = 0; r < 4; ++r) {
                    float p = fexp2(sacc[g][nt][r] - mn);
                    sacc[g][nt][r] = p;
                    rs += p;
                }
            rs += __shfl_xor(rs, 16, 64);
            rs += __shfl_xor(rs, 32, 64);
            l_run[g] = l_run[g] * alpha[g] + rs;
            m_run[g] = mn;
        }
        // skip O-rescale when no lane saw a new max (alpha==1 exactly)
        bool ns = (alpha[0] == 1.0f) & (alpha[1] == 1.0f);
        if (__ballot(ns) != ~0ull) {
            #pragma unroll
            for (int g = 0; g < 2; ++g)
                #pragma unroll
                for (int i = 0; i < 8; ++i)
                    #pragma unroll
                    for (int r = 0; r < 4; ++r) oacc[g][i][r] *= alpha[g];
        }
        // P^T -> per-wave LDS
        #pragma unroll
        for (int g = 0; g < 2; ++g)
            #pragma unroll
            for (int nt = 0; nt < 4; ++nt) {
                uint2 pk;
                pk.x = pk2_trunc(sacc[g][nt][0], sacc[g][nt][1]);
                pk.y = pk2_trunc(sacc[g][nt][2], sacc[g][nt][3]);
                *(uint2*)(&Ps[wave][(g * 16 + lm) * 88 + nt * 16 + lq * 4]) = pk;
            }
        // PV: O^T[d][q] += V^T[d][key] * P^T[key][q]; V-frags shared
        #pragma unroll
        for (int kc = 0; kc < 2; ++kc) {
            bf16x8 pf[2];
            #pragma unroll
            for (int g = 0; g < 2; ++g)
                pf[g] = *(const bf16x8*)(&Ps[wave][(g * 16 + lm) * 88 + kc * 32 + lq * 8]);
            #pragma unroll
            for (int mt = 0; mt < 8; ++mt) {
                bf16x8 vf = *(const bf16x8*)(&Vs[(mt * 16 + lm) * 88 + kc * 32 + lq * 8]);
                #pragma unroll
                for (int g = 0; g < 2; ++g)
                    oacc[g][mt] = __builtin_amdgcn_mfma_f32_16x16x32_bf16(vf, pf[g], oacc[g][mt], 0, 0, 0);
            }
        }
    }
    // epilogue
    #pragma unroll
    for (int g = 0; g < 2; ++g) {
        int qrow = q0 + wave * 32 + g * 16 + lm;
        if (qrow < S_TOT) {
            float inv = 1.0f / l_run[g];
            #pragma unroll
            for (int mt = 0; mt < 8; ++mt) {
                ushort4 pk;
                pk.x = f2bf(oacc[g][mt][0] * inv);
                pk.y = f2bf(oacc[g][mt][1] * inv);
                pk.z = f2bf(oacc[g][mt][2] * inv);
                pk.w = f2bf(oacc[g][mt][3] * inv);
                *(ushort4*)(o + (size_t)qrow * C_DIM + h * DHEAD + mt * 16 + lq * 4) = pk;
            }
        }
    }
}

// ------ Residual + transpose (S,C) bf16 -> (C,S) out (dual dtype) -----
__global__ __launch_bounds__(256) void resid_t(const unsigned short* __restrict__ proj,
                                               const void* __restrict__ x,
                                               const int* __restrict__ flag,
                                               void* __restrict__ out) {
    int isf32 = *flag;
    __shared__ float tile[32][33];
    int s0 = blockIdx.x * 32, c0 = blockIdx.y * 32;
    int tx = threadIdx.x, ty = threadIdx.y;   // (32,8)
    for (int r = 0; r < 4; ++r) {
        int sl = ty + 8 * r;
        tile[sl][tx] = bf2f(proj[(size_t)(s0 + sl) * C_DIM + (c0 + tx)]);
    }
    __syncthreads();
    for (int r = 0; r < 4; ++r) {
        int cl = ty + 8 * r;
        size_t idx = (size_t)(c0 + cl) * S_TOT + (s0 + tx);
        float val = ldin(x, idx, isf32) + tile[tx][cl];
        if (isf32) ((float*)out)[idx] = val;
        else       ((unsigned short*)out)[idx] = f2bf(val);
    }
}

extern "C" void kernel_launch(void* const* d_in, const int* in_sizes, int n_in,
                              void* d_out, int out_size, void* d_ws, size_t ws_size,
                              hipStream_t stream) {
    const void* x  = d_in[0];
    const void* Wq = d_in[1];
    const void* bq = d_in[2];
    const void* Wk = d_in[3];
    const void* bk = d_in[4];
    const void* Wv = d_in[5];
    const void* bv = d_in[6];
    const void* Wo = d_in[7];
    const void* bo = d_in[8];
    const void* bo_in = d_in[8];
    const void* gq = d_in[9];
    const void* gk = d_in[10];
    (void)bo_in;

    char* ws = (char*)d_ws;
    size_t off = 0;
    auto alloc = [&](size_t bytes) -> char* {
        char* p = ws + off;
        off += (bytes + 255) & ~(size_t)255;
        return p;
    };
    const size_t SC = (size_t)S_TOT * C_DIM;
    unsigned short* xn   = (unsigned short*)alloc(SC * 2);
    unsigned short* qb   = (unsigned short*)alloc(SC * 2);
    unsigned short* kb   = (unsigned short*)alloc(SC * 2);
    unsigned short* Ws0  = (unsigned short*)alloc((size_t)C_DIM * C_DIM * 2);
    unsigned short* Ws1  = (unsigned short*)alloc((size_t)C_DIM * C_DIM * 2);
    unsigned short* vecs = (unsigned short*)alloc((size_t)6 * C_DIM * 2);
    float* meanb         = (float*)alloc((size_t)S_TOT * 4);
    float* rstdb         = (float*)alloc((size_t)S_TOT * 4);
    int*   flag          = (int*)alloc(256);
    unsigned short* Vt   = (unsigned short*)d_out;   // [C][S] scratch in d_out
    unsigned short* ob   = xn;   // alias (xn dead after V-GEMM)
    unsigned short* proj = qb;   // alias (qb dead after attn)

    unsigned short* bq_b = vecs;
    unsigned short* bk_b = vecs + C_DIM;
    unsigned short* bv_b = vecs + 2 * C_DIM;
    unsigned short* bo_b = vecs + 3 * C_DIM;
    unsigned short* gq_b = vecs + 4 * C_DIM;
    unsigned short* gk_b = vecs + 5 * C_DIM;

    const float QSC = 0.12751745f;   // 1/sqrt(128) * log2(e)

    dim3 t328(32, 8);
    dim3 tgrid(S_TOT / 32, C_DIM / 32);             // (121, 48)
    dim3 ggrid((S_TOT + 63) / 64, C_DIM / 128);     // (61, 12)
    dim3 wgrid((C_DIM * C_DIM) / 2048, 2);          // (1152, 2)
    dim3 rgrid(S_TOT, 2);

    detect_vecs<<<1, 256, 0, stream>>>((const unsigned short*)x, bq, bk, bv, bo, gq, gk, flag, vecs);
    wconv2<<<wgrid, 256, 0, stream>>>(Wq, Wk, flag, Ws0, Ws1);
    ln_stats<<<NKT, 256, 0, stream>>>(x, flag, meanb, rstdb);
    ln_norm_t<<<tgrid, t328, 0, stream>>>(x, flag, meanb, rstdb, xn);

    gemm64<<<ggrid, 256, 0, stream>>>(xn, Ws0, bq_b, qb, 0);
    gemm64<<<ggrid, 256, 0, stream>>>(xn, Ws1, bk_b, kb, 0);
    rope2<<<rgrid, 256, 0, stream>>>(qb, kb, gq_b, gk_b, QSC);

    wconv2<<<wgrid, 256, 0, stream>>>(Wv, Wo, flag, Ws0, Ws1);  // slots free again
    gemm64<<<ggrid, 256, 0, stream>>>(xn, Ws0, bv_b, Vt, 1);

    attn_mfma<<<NHEAD * NQT, 256, 0, stream>>>(qb, kb, Vt, ob);

    gemm64<<<ggrid, 256, 0, stream>>>(ob, Ws1, bo_b, proj, 0);
    resid_t<<<tgrid, t328, 0, stream>>>(proj, x, flag, d_out);
}

// Round 8
// 739.775 us; speedup vs baseline: 1.0475x; 1.0475x over previous
//
#include <hip/hip_runtime.h>

#define S_TOT 3872
#define C_DIM 1536
#define NHEAD 12
#define DHEAD 128
#define TT 8
#define HH 22
#define WW 22
#define NKT 61          // ceil(3872/64): key tiles AND q tiles (64 q/block)

typedef __bf16 bf16x8 __attribute__((ext_vector_type(8)));
typedef float  f32x4  __attribute__((ext_vector_type(4)));
typedef unsigned short u16x8 __attribute__((ext_vector_type(8)));

__device__ __forceinline__ float bf2f(unsigned short u) {
    unsigned int v = ((unsigned int)u) << 16;
    float f; __builtin_memcpy(&f, &v, 4); return f;
}
__device__ __forceinline__ unsigned short f2bf(float f) {
    unsigned int u; __builtin_memcpy(&u, &f, 4);
    u += 0x7fffu + ((u >> 16) & 1u);
    return (unsigned short)(u >> 16);
}
__device__ __forceinline__ unsigned int pk2_trunc(float a, float b) {
    unsigned int ua, ub;
    __builtin_memcpy(&ua, &a, 4); __builtin_memcpy(&ub, &b, 4);
    return (ua >> 16) | (ub & 0xffff0000u);
}
__device__ __forceinline__ bf16x8 as_bf16x8(uint4 v) {
    bf16x8 r; __builtin_memcpy(&r, &v, 16); return r;
}
__device__ __forceinline__ float ldin(const void* p, size_t i, int isf32) {
    if (isf32) return ((const float*)p)[i];
    return bf2f(((const unsigned short*)p)[i]);
}
__device__ __forceinline__ float fexp2(float x) {
#if __has_builtin(__builtin_amdgcn_exp2f)
    return __builtin_amdgcn_exp2f(x);
#else
    return exp2f(x);
#endif
}
__device__ __forceinline__ void async16(const void* g, void* l) {
    __builtin_amdgcn_global_load_lds(
        (const __attribute__((address_space(1))) unsigned int*)g,
        (__attribute__((address_space(3))) unsigned int*)l, 16, 0, 0);
}

// ------- dtype detector + bias/gain conversion (1 block) --------------
__global__ void detect_vecs(const unsigned short* __restrict__ x,
                            const void* p0, const void* p1, const void* p2,
                            const void* p3, const void* p4, const void* p5,
                            int* __restrict__ flag, unsigned short* __restrict__ vecs) {
    __shared__ int cnt;
    if (threadIdx.x == 0) cnt = 0;
    __syncthreads();
    int c = 0;
    for (int i = 0; i < 8; ++i) {
        unsigned short u = x[threadIdx.x * 8 + i];
        int e = (u >> 7) & 0xFF;
        if (e >= 112 && e <= 143) c++;
    }
    atomicAdd(&cnt, c);
    __syncthreads();
    int isf32 = (cnt >= 1900) ? 0 : 1;
    if (threadIdx.x == 0) *flag = isf32;
    const void* ps[6] = {p0, p1, p2, p3, p4, p5};
    for (int v = 0; v < 6; ++v)
        for (int j = threadIdx.x; j < C_DIM; j += 256)
            vecs[v * C_DIM + j] = f2bf(ldin(ps[v], j, isf32));
}

// -------- two weight matrices -> bf16, grid (1152, 2) -----------------
__global__ __launch_bounds__(256) void wconv2(const void* __restrict__ sA,
                                              const void* __restrict__ sB,
                                              const int* __restrict__ flag,
                                              unsigned short* __restrict__ dA,
                                              unsigned short* __restrict__ dB) {
    const void* src = blockIdx.y ? sB : sA;
    unsigned short* dst = blockIdx.y ? dB : dA;
    size_t i = ((size_t)blockIdx.x * 256 + threadIdx.x) * 8;
    if (*flag) {
        const float* s = (const float*)src + i;
        float4 a = *(const float4*)s, b = *(const float4*)(s + 4);
        u16x8 o;
        o[0]=f2bf(a.x); o[1]=f2bf(a.y); o[2]=f2bf(a.z); o[3]=f2bf(a.w);
        o[4]=f2bf(b.x); o[5]=f2bf(b.y); o[6]=f2bf(b.z); o[7]=f2bf(b.w);
        *(u16x8*)(dst + i) = o;
    } else {
        *(u16x8*)(dst + i) = *(const u16x8*)((const unsigned short*)src + i);
    }
}

// ---------------- LayerNorm stats: grid 61, block (64 s x 4 cg) -------
__global__ __launch_bounds__(256) void ln_stats(const void* __restrict__ x,
                                                const int* __restrict__ flag,
                                                float* __restrict__ meanb,
                                                float* __restrict__ rstdb) {
    int isf32 = *flag;
    int sl = threadIdx.x & 63, cg = threadIdx.x >> 6;
    int s = blockIdx.x * 64 + sl;
    float sum = 0.f, sumsq = 0.f;
    if (s < S_TOT) {
        for (int c = cg; c < C_DIM; c += 4) {
            float v = ldin(x, (size_t)c * S_TOT + s, isf32);
            sum += v; sumsq += v * v;
        }
    }
    __shared__ float r0[4][64], r1[4][64];
    r0[cg][sl] = sum; r1[cg][sl] = sumsq;
    __syncthreads();
    if (cg == 0 && s < S_TOT) {
        float st = r0[0][sl] + r0[1][sl] + r0[2][sl] + r0[3][sl];
        float sq = r1[0][sl] + r1[1][sl] + r1[2][sl] + r1[3][sl];
        float m = st * (1.0f / C_DIM);
        float var = sq * (1.0f / C_DIM) - m * m;
        meanb[s] = m;
        rstdb[s] = rsqrtf(var + 1e-6f);
    }
}

// ------------- Normalize + transpose (C,S) -> (S,C) bf16 --------------
__global__ __launch_bounds__(256) void ln_norm_t(const void* __restrict__ x,
                                                 const int* __restrict__ flag,
                                                 const float* __restrict__ meanb,
                                                 const float* __restrict__ rstdb,
                                                 unsigned short* __restrict__ xn) {
    int isf32 = *flag;
    __shared__ float tile[32][33];
    int s0 = blockIdx.x * 32, c0 = blockIdx.y * 32;
    int tx = threadIdx.x, ty = threadIdx.y;   // (32,8)
    for (int r = 0; r < 4; ++r) {
        int cl = ty + 8 * r;
        tile[cl][tx] = ldin(x, (size_t)(c0 + cl) * S_TOT + (s0 + tx), isf32);
    }
    __syncthreads();
    for (int r = 0; r < 4; ++r) {
        int sl = ty + 8 * r;
        int s = s0 + sl, c = c0 + tx;
        xn[(size_t)s * C_DIM + c] = f2bf((tile[tx][sl] - meanb[s]) * rstdb[s]);
    }
}

// ------- MFMA GEMM 64x128, BK=64, group-padded DMA staging ------------
// Fused-output: cols n < C_DIM go to D0, n >= C_DIM to D1 (wave-uniform,
// 128-col blocks never straddle). bias indexed by global n.
__global__ __launch_bounds__(256) void gemm64(const unsigned short* __restrict__ A,
                                              const unsigned short* __restrict__ W,
                                              const unsigned short* __restrict__ bias,
                                              unsigned short* __restrict__ D0,
                                              unsigned short* __restrict__ D1,
                                              int transV) {
    __shared__ __align__(16) unsigned char As_[8 * 1056];    // 64 rows x 64
    __shared__ __align__(16) unsigned char Bs_[16 * 1056];   // 128 rows x 64
    int m0 = blockIdx.x * 64, n0 = blockIdx.y * 128;
    int tid = threadIdx.x;
    int wave = tid >> 6, lane = tid & 63;
    int lm = lane & 15, lq = lane >> 4;
    int l8 = lane >> 3, c8 = (lane & 7) * 8;

    f32x4 acc[4][2];
    #pragma unroll
    for (int a = 0; a < 4; ++a)
        #pragma unroll
        for (int b = 0; b < 2; ++b) acc[a][b] = (f32x4){0.f, 0.f, 0.f, 0.f};

    for (int k0 = 0; k0 < C_DIM; k0 += 64) {
        __syncthreads();
        #pragma unroll
        for (int t = 0; t < 6; ++t) {
            int g = wave * 6 + t;   // 0..23
            if (g < 8) {
                int row = m0 + g * 8 + l8; if (row > S_TOT - 1) row = S_TOT - 1;
                async16(A + (size_t)row * C_DIM + k0 + c8, As_ + g * 1056);
            } else {
                int gb = g - 8;
                int row = n0 + gb * 8 + l8;
                async16(W + (size_t)row * C_DIM + k0 + c8, Bs_ + gb * 1056);
            }
        }
        __syncthreads();
        bf16x8 af[4][2], bf[2][2];
        #pragma unroll
        for (int mb = 0; mb < 4; ++mb)
            #pragma unroll
            for (int kc = 0; kc < 2; ++kc)
                af[mb][kc] = *(const bf16x8*)(As_ + (2 * mb + (lm >> 3)) * 1056
                                              + (lm & 7) * 128 + kc * 64 + lq * 16);
        #pragma unroll
        for (int nb = 0; nb < 2; ++nb)
            #pragma unroll
            for (int kc = 0; kc < 2; ++kc)
                bf[nb][kc] = *(const bf16x8*)(Bs_ + (4 * wave + 2 * nb + (lm >> 3)) * 1056
                                              + (lm & 7) * 128 + kc * 64 + lq * 16);
        #pragma unroll
        for (int kc = 0; kc < 2; ++kc)
            #pragma unroll
            for (int mb = 0; mb < 4; ++mb)
                #pragma unroll
                for (int nb = 0; nb < 2; ++nb)
                    acc[mb][nb] = __builtin_amdgcn_mfma_f32_16x16x32_bf16(af[mb][kc], bf[nb][kc], acc[mb][nb], 0, 0, 0);
    }

    unsigned short* Dp = D0;
    int gnoff = 0;
    if (n0 >= C_DIM) { Dp = D1; gnoff = C_DIM; }

    if (!transV) {
        #pragma unroll
        for (int mb = 0; mb < 4; ++mb)
            #pragma unroll
            for (int nb = 0; nb < 2; ++nb) {
                int gn = n0 + wave * 32 + nb * 16 + lm;
                float bv = bf2f(bias[gn]);
                #pragma unroll
                for (int r = 0; r < 4; ++r) {
                    int gm = m0 + mb * 16 + lq * 4 + r;
                    if (gm < S_TOT) Dp[(size_t)gm * C_DIM + (gn - gnoff)] = f2bf(acc[mb][nb][r] + bv);
                }
            }
    } else {
        #pragma unroll
        for (int mb = 0; mb < 4; ++mb) {
            int gm0 = m0 + mb * 16 + lq * 4;
            if (gm0 >= S_TOT) continue;
            #pragma unroll
            for (int nb = 0; nb < 2; ++nb) {
                int gn = n0 + wave * 32 + nb * 16 + lm;
                float bv = bf2f(bias[gn]);
                ushort4 pk;
                pk.x = f2bf(acc[mb][nb][0] + bv);
                pk.y = f2bf(acc[mb][nb][1] + bv);
                pk.z = f2bf(acc[mb][nb][2] + bv);
                pk.w = f2bf(acc[mb][nb][3] + bv);
                *(ushort4*)(D0 + (size_t)gn * S_TOT + gm0) = pk;
            }
        }
    }
}

// ---------- RMSNorm + RoPE for Q and K in one launch, in-place --------
__global__ __launch_bounds__(256) void rope2(unsigned short* __restrict__ qbuf,
                                             unsigned short* __restrict__ kbuf,
                                             const unsigned short* __restrict__ gq,
                                             const unsigned short* __restrict__ gk,
                                             float qsc) {
    int s = blockIdx.x;
    unsigned short* row = (blockIdx.y ? kbuf : qbuf) + (size_t)s * C_DIM;
    const unsigned short* g = blockIdx.y ? gk : gq;
    float premul = blockIdx.y ? 1.0f : qsc;
    int tid = threadIdx.x;
    float ss = 0.f;
    for (int i = 0; i < 6; ++i) {
        float v = bf2f(row[tid + 256 * i]);
        ss += v * v;
    }
    for (int off = 32; off; off >>= 1) ss += __shfl_down(ss, off, 64);
    __shared__ float wsum[4];
    __shared__ float scale_sh;
    if ((tid & 63) == 0) wsum[tid >> 6] = ss;
    __syncthreads();
    if (tid == 0) {
        float tot = wsum[0] + wsum[1] + wsum[2] + wsum[3];
        scale_sh = rsqrtf(tot * (1.0f / C_DIM) + 1e-6f) * premul;
    }
    __syncthreads();
    float scale = scale_sh;

    int t  = s / (HH * WW);
    int rm = s % (HH * WW);
    int hh = rm / WW, ww = rm % WW;

    float e[3][2];
    int cols[3];
    for (int i = 0; i < 3; ++i) {
        int p = tid + 256 * i;
        int j = p & 63;
        int col0 = (p >> 6) * DHEAD + 2 * j;
        cols[i] = col0;
        float e0 = bf2f(row[col0])     * scale * bf2f(g[col0]);
        float e1 = bf2f(row[col0 + 1]) * scale * bf2f(g[col0 + 1]);
        float pos, fr;
        if (j < 22)       { pos = (float)t;  fr = (float)j        * (1.0f / 22.0f); }
        else if (j < 43)  { pos = (float)hh; fr = (float)(j - 22) * (1.0f / 21.0f); }
        else              { pos = (float)ww; fr = (float)(j - 43) * (1.0f / 21.0f); }
        float ang = pos * expf(fr * -9.210340371976184f);
        float c = cosf(ang), sn = sinf(ang);
        e[i][0] = e0 * c - e1 * sn;
        e[i][1] = e0 * sn + e1 * c;
    }
    for (int i = 0; i < 3; ++i) {
        row[cols[i]]     = f2bf(e[i][0]);
        row[cols[i] + 1] = f2bf(e[i][1]);
    }
}

// ---------------- MFMA flash attention v5 -----------------------------
// R6's 16q/wave shape (732 blocks) + V read DIRECT from global Vt[d][s]
// (L2-served; A-frag = 8 contiguous keys). No Vs in LDS: 27.5 KB ->
// up to 5 blocks/CU LDS-wise; VGPR capped via launch_bounds(256,3).
__global__ __launch_bounds__(256, 3) void attn_mfma(const unsigned short* __restrict__ q,
                                                    const unsigned short* __restrict__ kp,
                                                    const unsigned short* __restrict__ vt,
                                                    unsigned short* __restrict__ o) {
    __shared__ __align__(16) unsigned char Ks[16896];       // 16 groups * 1056B
    __shared__ __align__(16) unsigned short Ps[4][16 * 88]; // [wave][q16][keys]

    int h  = blockIdx.x / NKT;
    int qt = blockIdx.x % NKT;
    int q0 = qt * 64;
    int tid = threadIdx.x;
    int wave = tid >> 6, lane = tid & 63;
    int lm = lane & 15, lq = lane >> 4;

    // Q as B-operand fragments (lane = q-col, regs = d); pre-scaled
    bf16x8 qf[4];
    {
        int qr = q0 + wave * 16 + lm; if (qr >= S_TOT) qr = S_TOT - 1;
        const unsigned short* qptr = q + (size_t)qr * C_DIM + h * DHEAD + lq * 8;
        #pragma unroll
        for (int kc = 0; kc < 4; ++kc) qf[kc] = *(const bf16x8*)(qptr + kc * 32);
    }

    int kgrow = lane >> 4;
    size_t kcol = (size_t)(h * DHEAD + (lane & 15) * 8);
    int ksoff[4], kqoff[4];
    #pragma unroll
    for (int nt = 0; nt < 4; ++nt) ksoff[nt] = (nt * 4 + (lm >> 2)) * 1056 + (lm & 3) * 256;
    #pragma unroll
    for (int kc = 0; kc < 4; ++kc) kqoff[kc] = (kc * 4 + lq) * 16;

    // V direct-load base: lane lm covers d rows {mt*16+lm}
    const unsigned short* vbase = vt + (size_t)(h * DHEAD + lm) * S_TOT;

    f32x4 oacc[8];
    #pragma unroll
    for (int i = 0; i < 8; ++i) oacc[i] = (f32x4){0.f, 0.f, 0.f, 0.f};
    float m_run = -__builtin_inff(), l_run = 0.f;

    for (int kt = 0; kt < NKT; ++kt) {
        int k0 = kt * 64;
        __syncthreads();               // prev tile's Ks reads complete
        #pragma unroll
        for (int t = 0; t < 4; ++t) {
            int g = wave * 4 + t;
            int grow = k0 + g * 4 + kgrow; if (grow > S_TOT - 1) grow = S_TOT - 1;
            async16(kp + (size_t)grow * C_DIM + kcol, Ks + g * 1056);
        }
        __syncthreads();               // K landed (vmcnt drained at barrier)

        // issue all V loads for this tile up front (L2 latency hidden
        // under QK + softmax). Clamped frags correspond to P=0 keys.
        uint4 vr[2][8];
        #pragma unroll
        for (int kc = 0; kc < 2; ++kc) {
            int kb = k0 + kc * 32 + lq * 8;
            if (kb > S_TOT - 8) kb = S_TOT - 8;
            #pragma unroll
            for (int mt = 0; mt < 8; ++mt)
                vr[kc][mt] = *(const uint4*)(vbase + (size_t)mt * 16 * S_TOT + kb);
        }

        // S^T[key][q] = K * Q^T
        f32x4 sacc[4];
        #pragma unroll
        for (int nt = 0; nt < 4; ++nt) sacc[nt] = (f32x4){0.f, 0.f, 0.f, 0.f};
        #pragma unroll
        for (int kc = 0; kc < 4; ++kc)
            #pragma unroll
            for (int nt = 0; nt < 4; ++nt) {
                bf16x8 kf = *(const bf16x8*)(Ks + ksoff[nt] + kqoff[kc]);
                sacc[nt] = __builtin_amdgcn_mfma_f32_16x16x32_bf16(kf, qf[kc], sacc[nt], 0, 0, 0);
            }
        if (kt == NKT - 1) {
            #pragma unroll
            for (int nt = 0; nt < 4; ++nt)
                #pragma unroll
                for (int r = 0; r < 4; ++r)
                    if (k0 + nt * 16 + lq * 4 + r >= S_TOT) sacc[nt][r] = -__builtin_inff();
        }
        // online softmax, base-2, scalar state (lane owns q-col lm)
        float rmax = sacc[0][0];
        #pragma unroll
        for (int nt = 0; nt < 4; ++nt)
            #pragma unroll
            for (int r = 0; r < 4; ++r) rmax = fmaxf(rmax, sacc[nt][r]);
        rmax = fmaxf(rmax, __shfl_xor(rmax, 16, 64));
        rmax = fmaxf(rmax, __shfl_xor(rmax, 32, 64));
        float mn = fmaxf(m_run, rmax);
        float alpha = fexp2(m_run - mn);
        float rs = 0.f;
        #pragma unroll
        for (int nt = 0; nt < 4; ++nt)
            #pragma unroll
            for (int r = 0; r < 4; ++r) {
                float p = fexp2(sacc[nt][r] - mn);
                sacc[nt][r] = p;
                rs += p;
            }
        rs += __shfl_xor(rs, 16, 64);
        rs += __shfl_xor(rs, 32, 64);
        l_run = l_run * alpha + rs;
        m_run = mn;
        // P^T -> per-wave LDS (row q=lm, keys nt*16+lq*4, b64 writes)
        #pragma unroll
        for (int nt = 0; nt < 4; ++nt) {
            uint2 pk;
            pk.x = pk2_trunc(sacc[nt][0], sacc[nt][1]);
            pk.y = pk2_trunc(sacc[nt][2], sacc[nt][3]);
            *(uint2*)(&Ps[wave][lm * 88 + nt * 16 + lq * 4]) = pk;
        }
        // rescale O^T; skip if no lane saw a new max
        bool ns = (alpha == 1.0f);
        if (__ballot(ns) != ~0ull) {
            #pragma unroll
            for (int i = 0; i < 8; ++i)
                #pragma unroll
                for (int r = 0; r < 4; ++r) oacc[i][r] *= alpha;
        }
        // PV: O^T[d][q] += V^T[d][key] * P^T[key][q]; V from registers
        #pragma unroll
        for (int kc = 0; kc < 2; ++kc) {
            bf16x8 pf = *(const bf16x8*)(&Ps[wave][lm * 88 + kc * 32 + lq * 8]);
            #pragma unroll
            for (int mt = 0; mt < 8; ++mt)
                oacc[mt] = __builtin_amdgcn_mfma_f32_16x16x32_bf16(as_bf16x8(vr[kc][mt]), pf, oacc[mt], 0, 0, 0);
        }
    }
    // epilogue: lane owns q-column lm; d = mt*16 + lq*4 + r
    int qrow = q0 + wave * 16 + lm;
    if (qrow < S_TOT) {
        float inv = 1.0f / l_run;
        #pragma unroll
        for (int mt = 0; mt < 8; ++mt) {
            ushort4 pk;
            pk.x = f2bf(oacc[mt][0] * inv);
            pk.y = f2bf(oacc[mt][1] * inv);
            pk.z = f2bf(oacc[mt][2] * inv);
            pk.w = f2bf(oacc[mt][3] * inv);
            *(ushort4*)(o + (size_t)qrow * C_DIM + h * DHEAD + mt * 16 + lq * 4) = pk;
        }
    }
}

// ------ Residual + transpose (S,C) bf16 -> (C,S) out (dual dtype) -----
__global__ __launch_bounds__(256) void resid_t(const unsigned short* __restrict__ proj,
                                               const void* __restrict__ x,
                                               const int* __restrict__ flag,
                                               void* __restrict__ out) {
    int isf32 = *flag;
    __shared__ float tile[32][33];
    int s0 = blockIdx.x * 32, c0 = blockIdx.y * 32;
    int tx = threadIdx.x, ty = threadIdx.y;   // (32,8)
    for (int r = 0; r < 4; ++r) {
        int sl = ty + 8 * r;
        tile[sl][tx] = bf2f(proj[(size_t)(s0 + sl) * C_DIM + (c0 + tx)]);
    }
    __syncthreads();
    for (int r = 0; r < 4; ++r) {
        int cl = ty + 8 * r;
        size_t idx = (size_t)(c0 + cl) * S_TOT + (s0 + tx);
        float val = ldin(x, idx, isf32) + tile[tx][cl];
        if (isf32) ((float*)out)[idx] = val;
        else       ((unsigned short*)out)[idx] = f2bf(val);
    }
}

extern "C" void kernel_launch(void* const* d_in, const int* in_sizes, int n_in,
                              void* d_out, int out_size, void* d_ws, size_t ws_size,
                              hipStream_t stream) {
    const void* x  = d_in[0];
    const void* Wq = d_in[1];
    const void* bq = d_in[2];
    const void* Wk = d_in[3];
    const void* bk = d_in[4];
    const void* Wv = d_in[5];
    const void* bv = d_in[6];
    const void* Wo = d_in[7];
    const void* bo = d_in[8];
    const void* gq = d_in[9];
    const void* gk = d_in[10];

    char* ws = (char*)d_ws;
    size_t off = 0;
    auto alloc = [&](size_t bytes) -> char* {
        char* p = ws + off;
        off += (bytes + 255) & ~(size_t)255;
        return p;
    };
    const size_t SC = (size_t)S_TOT * C_DIM;
    unsigned short* xn   = (unsigned short*)alloc(SC * 2);
    unsigned short* qb   = (unsigned short*)alloc(SC * 2);
    unsigned short* kb   = (unsigned short*)alloc(SC * 2);
    unsigned short* Ws0  = (unsigned short*)alloc((size_t)C_DIM * C_DIM * 2);
    unsigned short* Ws1  = (unsigned short*)alloc((size_t)C_DIM * C_DIM * 2);  // contiguous after Ws0
    unsigned short* vecs = (unsigned short*)alloc((size_t)6 * C_DIM * 2);
    float* meanb         = (float*)alloc((size_t)S_TOT * 4);
    float* rstdb         = (float*)alloc((size_t)S_TOT * 4);
    int*   flag          = (int*)alloc(256);
    unsigned short* Vt   = (unsigned short*)d_out;   // [C][S] scratch in d_out
    unsigned short* ob   = xn;   // alias (xn dead after V-GEMM)
    unsigned short* proj = qb;   // alias (qb dead after attn)

    unsigned short* bq_b = vecs;                 // bq | bk contiguous (fused gemm)
    unsigned short* bv_b = vecs + 2 * C_DIM;
    unsigned short* bo_b = vecs + 3 * C_DIM;
    unsigned short* gq_b = vecs + 4 * C_DIM;
    unsigned short* gk_b = vecs + 5 * C_DIM;

    const float QSC = 0.12751745f;   // 1/sqrt(128) * log2(e)

    dim3 t328(32, 8);
    dim3 tgrid(S_TOT / 32, C_DIM / 32);             // (121, 48)
    dim3 gqk((S_TOT + 63) / 64, 2 * C_DIM / 128);   // (61, 24) fused Q+K
    dim3 g1((S_TOT + 63) / 64, C_DIM / 128);        // (61, 12)
    dim3 wgrid((C_DIM * C_DIM) / 2048, 2);          // (1152, 2)
    dim3 rgrid(S_TOT, 2);

    detect_vecs<<<1, 256, 0, stream>>>((const unsigned short*)x, bq, bk, bv, bo, gq, gk, flag, vecs);
    wconv2<<<wgrid, 256, 0, stream>>>(Wq, Wk, flag, Ws0, Ws1);
    ln_stats<<<NKT, 256, 0, stream>>>(x, flag, meanb, rstdb);
    ln_norm_t<<<tgrid, t328, 0, stream>>>(x, flag, meanb, rstdb, xn);

    // fused Q+K projection: W = [Wq; Wk] (Ws0||Ws1 contiguous), bias bq||bk
    gemm64<<<gqk, 256, 0, stream>>>(xn, Ws0, bq_b, qb, kb, 0);
    rope2<<<rgrid, 256, 0, stream>>>(qb, kb, gq_b, gk_b, QSC);

    wconv2<<<wgrid, 256, 0, stream>>>(Wv, Wo, flag, Ws0, Ws1);  // slots free again
    gemm64<<<g1, 256, 0, stream>>>(xn, Ws0, bv_b, Vt, Vt, 1);

    attn_mfma<<<NHEAD * NKT, 256, 0, stream>>>(qb, kb, Vt, ob);

    gemm64<<<g1, 256, 0, stream>>>(ob, Ws1, bo_b, proj, proj, 0);
    resid_t<<<tgrid, t328, 0, stream>>>(proj, x, flag, d_out);
}